// Round 2
// baseline (398.313 us; speedup 1.0000x reference)
//
#include <hip/hip_runtime.h>
#include <stdint.h>

#define T_TOK 2048
#define H_DIM 1024
#define E_NUM 16
#define I_DIM 1024
#define TOTAL_ROWS (2 * T_TOK)   // exactly T*K assignment rows

typedef short bf16x8 __attribute__((ext_vector_type(8)));
typedef float f32x4 __attribute__((ext_vector_type(4)));

// Proper addrspace casts (addrspacecast, NOT integer truncation — the flat
// shared aperture's low 32 bits are not the LDS offset; truncation faults).
__device__ __forceinline__ void async_copy16(const void* g, void* l) {
  __builtin_amdgcn_global_load_lds(
      (const __attribute__((address_space(1))) void*)g,
      (__attribute__((address_space(3))) void*)l, 16, 0, 0);
}

// fp32 -> bf16 round-to-nearest-even (inputs finite, no NaN handling needed)
__device__ __forceinline__ uint32_t f2bf(float f) {
  uint32_t u = __float_as_uint(f);
  return (u + 0x7FFFu + ((u >> 16) & 1u)) >> 16;
}
__device__ __forceinline__ uint32_t pk2bf(float lo, float hi) {
  return f2bf(lo) | (f2bf(hi) << 16);
}

// ---------------------------------------------------------------------------
// Kernel 1: router (fp32 exact) + x -> bf16 conversion.
// 1 wave handles 4 tokens; router_w float4s reused across the 4 tokens.
// ---------------------------------------------------------------------------
__global__ __launch_bounds__(256) void router_kernel(
    const float* __restrict__ x, const float* __restrict__ rw,
    uint16_t* __restrict__ xbf, int* __restrict__ counts,
    int* __restrict__ tokens, float* __restrict__ wts) {
  const int wave = blockIdx.x * 4 + (threadIdx.x >> 6);
  const int lane = threadIdx.x & 63;
  const int t0 = wave * 4;

  float acc[4][E_NUM];
#pragma unroll
  for (int tk = 0; tk < 4; ++tk)
#pragma unroll
    for (int e = 0; e < E_NUM; ++e) acc[tk][e] = 0.f;

#pragma unroll
  for (int rep = 0; rep < 4; ++rep) {
    const int h0 = rep * 256 + lane * 4;
    float4 xv[4];
#pragma unroll
    for (int tk = 0; tk < 4; ++tk) {
      xv[tk] = *(const float4*)(x + (size_t)(t0 + tk) * H_DIM + h0);
      uint2 p;
      p.x = pk2bf(xv[tk].x, xv[tk].y);
      p.y = pk2bf(xv[tk].z, xv[tk].w);
      *(uint2*)(xbf + (size_t)(t0 + tk) * H_DIM + h0) = p;
    }
#pragma unroll
    for (int e = 0; e < E_NUM; ++e) {
      float4 rv = *(const float4*)(rw + (size_t)e * H_DIM + h0);
#pragma unroll
      for (int tk = 0; tk < 4; ++tk)
        acc[tk][e] += xv[tk].x * rv.x + xv[tk].y * rv.y +
                      xv[tk].z * rv.z + xv[tk].w * rv.w;
    }
  }

#pragma unroll
  for (int tk = 0; tk < 4; ++tk)
#pragma unroll
    for (int e = 0; e < E_NUM; ++e) {
      float v = acc[tk][e];
#pragma unroll
      for (int off = 32; off > 0; off >>= 1) v += __shfl_xor(v, off);
      acc[tk][e] = v;
    }

  if (lane == 0) {
#pragma unroll
    for (int tk = 0; tk < 4; ++tk) {
      float s[E_NUM];
#pragma unroll
      for (int e = 0; e < E_NUM; ++e) s[e] = 1.f / (1.f + expf(-acc[tk][e]));
      // top-2, ties -> lower index (matches lax.top_k)
      int i1 = 0;
      float v1 = s[0];
#pragma unroll
      for (int e = 1; e < E_NUM; ++e)
        if (s[e] > v1) { v1 = s[e]; i1 = e; }
      int i2 = -1;
      float v2 = -1.f;
#pragma unroll
      for (int e = 0; e < E_NUM; ++e)
        if (e != i1 && s[e] > v2) { v2 = s[e]; i2 = e; }
      const float inv = 1.f / (v1 + v2 + 1e-20f);
      const int t = t0 + tk;
      int s1 = atomicAdd(&counts[i1], 1);
      tokens[i1 * T_TOK + s1] = t;
      wts[i1 * T_TOK + s1] = v1 * inv;
      int s2 = atomicAdd(&counts[i2], 1);
      tokens[i2 * T_TOK + s2] = t;
      wts[i2 * T_TOK + s2] = v2 * inv;
    }
  }
}

// ---------------------------------------------------------------------------
// Kernel 2: exclusive prefix sum over the 16 expert counts.
// ---------------------------------------------------------------------------
__global__ void offsets_kernel(const int* __restrict__ counts,
                               int* __restrict__ offsets) {
  if (threadIdx.x == 0) {
    int a = 0;
    for (int e = 0; e < E_NUM; ++e) {
      offsets[e] = a;
      a += counts[e];
    }
    offsets[E_NUM] = a;
  }
}

// ---------------------------------------------------------------------------
// Kernel 3: GEMM1  h = silu(x@gateT) * (x@upT) * route_wt   (per expert)
// BM=128 BN=64 BK=32, 4 waves (2x2), dual accumulators (gate & up).
// A rows gathered through the expert token list, staged via global_load_lds.
// B (fp32 weights) converted to bf16 in-register during staging.
// ---------------------------------------------------------------------------
__global__ __launch_bounds__(256) void gemm1_kernel(
    const uint16_t* __restrict__ xbf, const float* __restrict__ gate,
    const float* __restrict__ up, const int* __restrict__ counts,
    const int* __restrict__ offsets, const int* __restrict__ tokens,
    const float* __restrict__ wts, uint16_t* __restrict__ hbuf) {
  const int e = blockIdx.z;
  const int count = counts[e];
  const int m0 = blockIdx.y * 128;
  if (m0 >= count) return;
  const int n0 = blockIdx.x * 64;

  __shared__ __align__(16) uint16_t As[128 * 32];
  __shared__ __align__(16) uint16_t Bgs[64 * 32];
  __shared__ __align__(16) uint16_t Bus[64 * 32];
  __shared__ int tok_s[128];
  __shared__ float wt_s[128];

  const int tid = threadIdx.x;
  if (tid < 128) {
    const int slot = m0 + tid;
    int tk = 0;
    float w = 0.f;
    if (slot < count) {
      tk = tokens[e * T_TOK + slot];
      w = wts[e * T_TOK + slot];
    }
    tok_s[tid] = tk;
    wt_s[tid] = w;
  }
  __syncthreads();

  // A staging: 512 16B chunks, 2 per thread; chunk ci -> row ci>>2, quarter ci&3
  const int ci0 = tid, ci1 = 256 + tid;
  const uint16_t* a_g0 = xbf + (size_t)tok_s[ci0 >> 2] * H_DIM + (ci0 & 3) * 8;
  const uint16_t* a_g1 = xbf + (size_t)tok_s[ci1 >> 2] * H_DIM + (ci1 & 3) * 8;
  uint16_t* a_l0 = As + ci0 * 8;
  uint16_t* a_l1 = As + ci1 * 8;

  // B staging: 64 rows x 32 K, 8 fp32 per thread per matrix
  const int br = tid >> 2, bc = (tid & 3) * 8;
  const float* g_g = gate + ((size_t)e * I_DIM + n0 + br) * H_DIM + bc;
  const float* u_g = up + ((size_t)e * I_DIM + n0 + br) * H_DIM + bc;
  uint16_t* bg_l = Bgs + br * 32 + bc;
  uint16_t* bu_l = Bus + br * 32 + bc;

  const int wave = tid >> 6, lane = tid & 63;
  const int wm = (wave & 1) * 64, wn = (wave >> 1) * 32;
  const int lc = lane & 15, lq = lane >> 4;

  f32x4 accg[4][2], accu[4][2];
  const f32x4 zero4 = {0.f, 0.f, 0.f, 0.f};
#pragma unroll
  for (int i = 0; i < 4; ++i)
#pragma unroll
    for (int j = 0; j < 2; ++j) {
      accg[i][j] = zero4;
      accu[i][j] = zero4;
    }

  const int a_off = (wm + lc) * 32 + lq * 8;
  const int b_off = (wn + lc) * 32 + lq * 8;

  for (int k0 = 0; k0 < H_DIM; k0 += 32) {
    __syncthreads();
    async_copy16(a_g0 + k0, a_l0);
    async_copy16(a_g1 + k0, a_l1);
    float4 gv0 = *(const float4*)(g_g + k0);
    float4 gv1 = *(const float4*)(g_g + k0 + 4);
    float4 uv0 = *(const float4*)(u_g + k0);
    float4 uv1 = *(const float4*)(u_g + k0 + 4);
    uint4 gp, upk;
    gp.x = pk2bf(gv0.x, gv0.y);
    gp.y = pk2bf(gv0.z, gv0.w);
    gp.z = pk2bf(gv1.x, gv1.y);
    gp.w = pk2bf(gv1.z, gv1.w);
    upk.x = pk2bf(uv0.x, uv0.y);
    upk.y = pk2bf(uv0.z, uv0.w);
    upk.z = pk2bf(uv1.x, uv1.y);
    upk.w = pk2bf(uv1.z, uv1.w);
    *(uint4*)bg_l = gp;
    *(uint4*)bu_l = upk;
    __syncthreads();

    bf16x8 af[4], bgf[2], buf2[2];
#pragma unroll
    for (int im = 0; im < 4; ++im)
      af[im] = *(const bf16x8*)(As + a_off + im * 16 * 32);
#pragma unroll
    for (int in = 0; in < 2; ++in) {
      bgf[in] = *(const bf16x8*)(Bgs + b_off + in * 16 * 32);
      buf2[in] = *(const bf16x8*)(Bus + b_off + in * 16 * 32);
    }
#pragma unroll
    for (int im = 0; im < 4; ++im)
#pragma unroll
      for (int in = 0; in < 2; ++in) {
        accg[im][in] = __builtin_amdgcn_mfma_f32_16x16x32_bf16(
            af[im], bgf[in], accg[im][in], 0, 0, 0);
        accu[im][in] = __builtin_amdgcn_mfma_f32_16x16x32_bf16(
            af[im], buf2[in], accu[im][in], 0, 0, 0);
      }
  }

  const int off_e = offsets[e];
#pragma unroll
  for (int im = 0; im < 4; ++im) {
#pragma unroll
    for (int r = 0; r < 4; ++r) {
      const int row = wm + im * 16 + lq * 4 + r;  // C/D: row=(lane>>4)*4+reg
      const int slot = m0 + row;
      if (slot < count) {
        const float w = wt_s[row];
        uint16_t* hrow = hbuf + (size_t)(off_e + slot) * I_DIM + n0 + wn;
#pragma unroll
        for (int in = 0; in < 2; ++in) {
          const float g = accg[im][in][r];
          const float u = accu[im][in][r];
          const float hv = g / (1.f + __expf(-g)) * u * w;
          hrow[in * 16 + lc] = (uint16_t)f2bf(hv);  // C/D: col=lane&15
        }
      }
    }
  }
}

// ---------------------------------------------------------------------------
// Kernel 4: GEMM2  out[tok] += h @ down_wT   (per expert, atomic combine)
// BM=128 BN=128 BK=32, 4 waves (2x2), 64x64 per wave.
// ---------------------------------------------------------------------------
__global__ __launch_bounds__(256) void gemm2_kernel(
    const uint16_t* __restrict__ hbuf, const float* __restrict__ down,
    const int* __restrict__ counts, const int* __restrict__ offsets,
    const int* __restrict__ tokens, float* __restrict__ out) {
  const int e = blockIdx.z;
  const int count = counts[e];
  const int m0 = blockIdx.y * 128;
  if (m0 >= count) return;
  const int n0 = blockIdx.x * 128;

  __shared__ __align__(16) uint16_t As[128 * 32];
  __shared__ __align__(16) uint16_t Bs[128 * 32];
  __shared__ int tok_s[128];

  const int tid = threadIdx.x;
  const int off_e = offsets[e];
  if (tid < 128) {
    const int slot = m0 + tid;
    tok_s[tid] = (slot < count) ? tokens[e * T_TOK + slot] : 0;
  }

  const int ci0 = tid, ci1 = 256 + tid;
  int r0 = off_e + m0 + (ci0 >> 2);
  int r1 = off_e + m0 + (ci1 >> 2);
  if (r0 > TOTAL_ROWS - 1) r0 = TOTAL_ROWS - 1;  // ragged tail: junk rows,
  if (r1 > TOTAL_ROWS - 1) r1 = TOTAL_ROWS - 1;  // never stored
  const uint16_t* a_g0 = hbuf + (size_t)r0 * I_DIM + (ci0 & 3) * 8;
  const uint16_t* a_g1 = hbuf + (size_t)r1 * I_DIM + (ci1 & 3) * 8;
  uint16_t* a_l0 = As + ci0 * 8;
  uint16_t* a_l1 = As + ci1 * 8;

  const int br = tid >> 1, bc = (tid & 1) * 16;
  const float* d_g = down + ((size_t)e * H_DIM + n0 + br) * I_DIM + bc;
  uint16_t* b_l = Bs + br * 32 + bc;

  const int wave = tid >> 6, lane = tid & 63;
  const int wm = (wave & 1) * 64, wn = (wave >> 1) * 64;
  const int lc = lane & 15, lq = lane >> 4;

  f32x4 acc[4][4];
  const f32x4 zero4 = {0.f, 0.f, 0.f, 0.f};
#pragma unroll
  for (int i = 0; i < 4; ++i)
#pragma unroll
    for (int j = 0; j < 4; ++j) acc[i][j] = zero4;

  const int a_off = (wm + lc) * 32 + lq * 8;
  const int b_off = (wn + lc) * 32 + lq * 8;

  for (int k0 = 0; k0 < I_DIM; k0 += 32) {
    __syncthreads();
    async_copy16(a_g0 + k0, a_l0);
    async_copy16(a_g1 + k0, a_l1);
    float4 v0 = *(const float4*)(d_g + k0);
    float4 v1 = *(const float4*)(d_g + k0 + 4);
    float4 v2 = *(const float4*)(d_g + k0 + 8);
    float4 v3 = *(const float4*)(d_g + k0 + 12);
    uint4 p0, p1;
    p0.x = pk2bf(v0.x, v0.y);
    p0.y = pk2bf(v0.z, v0.w);
    p0.z = pk2bf(v1.x, v1.y);
    p0.w = pk2bf(v1.z, v1.w);
    p1.x = pk2bf(v2.x, v2.y);
    p1.y = pk2bf(v2.z, v2.w);
    p1.z = pk2bf(v3.x, v3.y);
    p1.w = pk2bf(v3.z, v3.w);
    *(uint4*)b_l = p0;
    *(uint4*)(b_l + 8) = p1;
    __syncthreads();

    bf16x8 af[4], bf[4];
#pragma unroll
    for (int im = 0; im < 4; ++im)
      af[im] = *(const bf16x8*)(As + a_off + im * 16 * 32);
#pragma unroll
    for (int in = 0; in < 4; ++in)
      bf[in] = *(const bf16x8*)(Bs + b_off + in * 16 * 32);
#pragma unroll
    for (int im = 0; im < 4; ++im)
#pragma unroll
      for (int in = 0; in < 4; ++in)
        acc[im][in] = __builtin_amdgcn_mfma_f32_16x16x32_bf16(
            af[im], bf[in], acc[im][in], 0, 0, 0);
  }

#pragma unroll
  for (int im = 0; im < 4; ++im) {
#pragma unroll
    for (int r = 0; r < 4; ++r) {
      const int row = wm + im * 16 + lq * 4 + r;
      const int slot = m0 + row;
      if (slot < count) {
        float* orow = out + (size_t)tok_s[row] * H_DIM + n0 + wn;
#pragma unroll
        for (int in = 0; in < 4; ++in)
          atomicAdd(orow + in * 16 + lc, acc[im][in][r]);
      }
    }
  }
}

// ---------------------------------------------------------------------------
extern "C" void kernel_launch(void* const* d_in, const int* in_sizes, int n_in,
                              void* d_out, int out_size, void* d_ws,
                              size_t ws_size, hipStream_t stream) {
  const float* x = (const float*)d_in[0];
  const float* rw = (const float*)d_in[1];
  const float* gate = (const float*)d_in[2];
  const float* up = (const float*)d_in[3];
  const float* down = (const float*)d_in[4];
  float* out = (float*)d_out;

  uint8_t* ws = (uint8_t*)d_ws;
  int* counts = (int*)ws;                                  // 16 ints
  int* offsets = (int*)(ws + 128);                         // 17 ints
  int* tokens = (int*)(ws + 1024);                         // 16*2048*4 = 128 KiB
  float* wts = (float*)(ws + 1024 + 131072);               // 128 KiB
  uint16_t* xbf = (uint16_t*)(ws + 1024 + 262144);         // 4 MiB
  uint16_t* hbuf = (uint16_t*)(ws + 1024 + 262144 + 4194304);  // 8 MiB

  hipMemsetAsync(counts, 0, 128, stream);
  hipMemsetAsync(out, 0, (size_t)out_size * sizeof(float), stream);

  router_kernel<<<128, 256, 0, stream>>>(x, rw, xbf, counts, tokens, wts);
  offsets_kernel<<<1, 64, 0, stream>>>(counts, offsets);
  gemm1_kernel<<<dim3(16, 16, 16), 256, 0, stream>>>(
      xbf, gate, up, counts, offsets, tokens, wts, hbuf);
  gemm2_kernel<<<dim3(8, 16, 16), 256, 0, stream>>>(hbuf, down, counts,
                                                    offsets, tokens, out);
}

// Round 3
// 368.514 us; speedup vs baseline: 1.0809x; 1.0809x over previous
//
#include <hip/hip_runtime.h>
#include <stdint.h>

#define T_TOK 2048
#define H_DIM 1024
#define E_NUM 16
#define I_DIM 1024
#define TOTAL_ROWS (2 * T_TOK)   // exactly T*K assignment rows

typedef short bf16x8 __attribute__((ext_vector_type(8)));
typedef float f32x4 __attribute__((ext_vector_type(4)));

__device__ __forceinline__ void async_copy16(const void* g, void* l) {
  __builtin_amdgcn_global_load_lds(
      (const __attribute__((address_space(1))) void*)g,
      (__attribute__((address_space(3))) void*)l, 16, 0, 0);
}

// fp32 -> bf16 round-to-nearest-even (inputs finite)
__device__ __forceinline__ uint32_t f2bf(float f) {
  uint32_t u = __float_as_uint(f);
  return (u + 0x7FFFu + ((u >> 16) & 1u)) >> 16;
}
__device__ __forceinline__ uint32_t pk2bf(float lo, float hi) {
  return f2bf(lo) | (f2bf(hi) << 16);
}

// load 8 fp32, pack to 8 bf16, write 16B to LDS
__device__ __forceinline__ void stage8(const float* g, uint16_t* l) {
  float4 v0 = *(const float4*)g;
  float4 v1 = *(const float4*)(g + 4);
  uint4 p;
  p.x = pk2bf(v0.x, v0.y);
  p.y = pk2bf(v0.z, v0.w);
  p.z = pk2bf(v1.x, v1.y);
  p.w = pk2bf(v1.z, v1.w);
  *(uint4*)l = p;
}

// ---------------------------------------------------------------------------
// Kernel 1: router (fp32 exact) + x -> bf16 conversion.
// ---------------------------------------------------------------------------
__global__ __launch_bounds__(256) void router_kernel(
    const float* __restrict__ x, const float* __restrict__ rw,
    uint16_t* __restrict__ xbf, int* __restrict__ counts,
    int* __restrict__ tokens, float* __restrict__ wts) {
  const int wave = blockIdx.x * 4 + (threadIdx.x >> 6);
  const int lane = threadIdx.x & 63;
  const int t0 = wave * 4;

  float acc[4][E_NUM];
#pragma unroll
  for (int tk = 0; tk < 4; ++tk)
#pragma unroll
    for (int e = 0; e < E_NUM; ++e) acc[tk][e] = 0.f;

#pragma unroll
  for (int rep = 0; rep < 4; ++rep) {
    const int h0 = rep * 256 + lane * 4;
    float4 xv[4];
#pragma unroll
    for (int tk = 0; tk < 4; ++tk) {
      xv[tk] = *(const float4*)(x + (size_t)(t0 + tk) * H_DIM + h0);
      uint2 p;
      p.x = pk2bf(xv[tk].x, xv[tk].y);
      p.y = pk2bf(xv[tk].z, xv[tk].w);
      *(uint2*)(xbf + (size_t)(t0 + tk) * H_DIM + h0) = p;
    }
#pragma unroll
    for (int e = 0; e < E_NUM; ++e) {
      float4 rv = *(const float4*)(rw + (size_t)e * H_DIM + h0);
#pragma unroll
      for (int tk = 0; tk < 4; ++tk)
        acc[tk][e] += xv[tk].x * rv.x + xv[tk].y * rv.y +
                      xv[tk].z * rv.z + xv[tk].w * rv.w;
    }
  }

#pragma unroll
  for (int tk = 0; tk < 4; ++tk)
#pragma unroll
    for (int e = 0; e < E_NUM; ++e) {
      float v = acc[tk][e];
#pragma unroll
      for (int off = 32; off > 0; off >>= 1) v += __shfl_xor(v, off);
      acc[tk][e] = v;
    }

  if (lane == 0) {
#pragma unroll
    for (int tk = 0; tk < 4; ++tk) {
      float s[E_NUM];
#pragma unroll
      for (int e = 0; e < E_NUM; ++e) s[e] = 1.f / (1.f + expf(-acc[tk][e]));
      int i1 = 0;
      float v1 = s[0];
#pragma unroll
      for (int e = 1; e < E_NUM; ++e)
        if (s[e] > v1) { v1 = s[e]; i1 = e; }
      int i2 = -1;
      float v2 = -1.f;
#pragma unroll
      for (int e = 0; e < E_NUM; ++e)
        if (e != i1 && s[e] > v2) { v2 = s[e]; i2 = e; }
      const float inv = 1.f / (v1 + v2 + 1e-20f);
      const int t = t0 + tk;
      int s1 = atomicAdd(&counts[i1], 1);
      tokens[i1 * T_TOK + s1] = t;
      wts[i1 * T_TOK + s1] = v1 * inv;
      int s2 = atomicAdd(&counts[i2], 1);
      tokens[i2 * T_TOK + s2] = t;
      wts[i2 * T_TOK + s2] = v2 * inv;
    }
  }
}

// ---------------------------------------------------------------------------
// Kernel 2: exclusive prefix sum over the 16 expert counts.
// ---------------------------------------------------------------------------
__global__ void offsets_kernel(const int* __restrict__ counts,
                               int* __restrict__ offsets) {
  if (threadIdx.x == 0) {
    int a = 0;
    for (int e = 0; e < E_NUM; ++e) {
      offsets[e] = a;
      a += counts[e];
    }
    offsets[E_NUM] = a;
  }
}

// ---------------------------------------------------------------------------
// LDS tile layout (both GEMMs): 64 rows x 64 k of bf16, stored as 16B chunks.
// chunk(m,kq) lives at index m*8 + (kq ^ (m&7)); the XOR spreads the 8
// fragment rows a b128 read touches across all 8 bank clusters (2-way
// residual aliasing = free, m136). Works with global_load_lds because the
// per-lane SOURCE address is free even though the LDS dst is base+lane*16.
// ---------------------------------------------------------------------------

// ---------------------------------------------------------------------------
// Kernel 3: GEMM1  h = silu(x@gateT) * (x@upT) * route_wt   (per expert)
// BM=64 BN=64 BK=64, 4 waves (2x2 of 32x32), dual gate/up accumulators.
// ~1024 active blocks, 24.5 KB LDS, 4 blocks/CU for barrier-staggered TLP.
// ---------------------------------------------------------------------------
__global__ __launch_bounds__(256, 4) void gemm1_kernel(
    const uint16_t* __restrict__ xbf, const float* __restrict__ gate,
    const float* __restrict__ up, const int* __restrict__ counts,
    const int* __restrict__ offsets, const int* __restrict__ tokens,
    const float* __restrict__ wts, uint16_t* __restrict__ hbuf) {
  const int e = blockIdx.z;
  const int count = counts[e];
  const int m0 = blockIdx.y * 64;
  if (m0 >= count) return;
  const int n0 = blockIdx.x * 64;

  __shared__ __align__(16) uint16_t As[64 * 64];
  __shared__ __align__(16) uint16_t Bgs[64 * 64];
  __shared__ __align__(16) uint16_t Bus[64 * 64];
  __shared__ int tok_s[64];
  __shared__ float wt_s[64];

  const int tid = threadIdx.x;
  if (tid < 64) {
    const int slot = m0 + tid;
    int tk = 0;
    float w = 0.f;
    if (slot < count) {
      tk = tokens[e * T_TOK + slot];
      w = wts[e * T_TOK + slot];
    }
    tok_s[tid] = tk;
    wt_s[tid] = w;
  }
  __syncthreads();

  // Two 16B chunks per thread per tile: c0=tid, c1=tid+256.
  const int c0 = tid, c1 = tid + 256;
  const int m_a0 = c0 >> 3, m_a1 = c1 >> 3;
  const int kq0 = (c0 & 7) ^ (m_a0 & 7);
  const int kq1 = (c1 & 7) ^ (m_a1 & 7);

  const uint16_t* a_g0 = xbf + (size_t)tok_s[m_a0] * H_DIM + kq0 * 8;
  const uint16_t* a_g1 = xbf + (size_t)tok_s[m_a1] * H_DIM + kq1 * 8;
  uint16_t* a_l0 = As + c0 * 8;
  uint16_t* a_l1 = As + c1 * 8;

  const float* g_g0 = gate + ((size_t)e * I_DIM + n0 + m_a0) * H_DIM + kq0 * 8;
  const float* g_g1 = gate + ((size_t)e * I_DIM + n0 + m_a1) * H_DIM + kq1 * 8;
  const float* u_g0 = up + ((size_t)e * I_DIM + n0 + m_a0) * H_DIM + kq0 * 8;
  const float* u_g1 = up + ((size_t)e * I_DIM + n0 + m_a1) * H_DIM + kq1 * 8;
  uint16_t* bg_l0 = Bgs + c0 * 8;
  uint16_t* bg_l1 = Bgs + c1 * 8;
  uint16_t* bu_l0 = Bus + c0 * 8;
  uint16_t* bu_l1 = Bus + c1 * 8;

  const int wave = tid >> 6, lane = tid & 63;
  const int wm = (wave & 1) * 32, wn = (wave >> 1) * 32;
  const int lc = lane & 15, lq = lane >> 4;
  const int l7 = lc & 7;  // (row&7) for every fragment row (rows step by 16)

  f32x4 accg[2][2], accu[2][2];
  const f32x4 zero4 = {0.f, 0.f, 0.f, 0.f};
#pragma unroll
  for (int i = 0; i < 2; ++i)
#pragma unroll
    for (int j = 0; j < 2; ++j) {
      accg[i][j] = zero4;
      accu[i][j] = zero4;
    }

  // fragment base offsets (uint16 units): row*64 ; swizzled k added per kstep
  const int am[2] = {(wm + lc) * 64, (wm + 16 + lc) * 64};
  const int bn[2] = {(wn + lc) * 64, (wn + 16 + lc) * 64};

  for (int k0 = 0; k0 < H_DIM; k0 += 64) {
    __syncthreads();
    async_copy16(a_g0 + k0, a_l0);
    async_copy16(a_g1 + k0, a_l1);
    stage8(g_g0 + k0, bg_l0);
    stage8(g_g1 + k0, bg_l1);
    stage8(u_g0 + k0, bu_l0);
    stage8(u_g1 + k0, bu_l1);
    __syncthreads();

#pragma unroll
    for (int ks = 0; ks < 2; ++ks) {
      const int kswz = (((ks * 4 + lq) ^ l7)) * 8;
      bf16x8 af[2], bg[2], bu[2];
#pragma unroll
      for (int i = 0; i < 2; ++i) {
        af[i] = *(const bf16x8*)(As + am[i] + kswz);
        bg[i] = *(const bf16x8*)(Bgs + bn[i] + kswz);
        bu[i] = *(const bf16x8*)(Bus + bn[i] + kswz);
      }
#pragma unroll
      for (int im = 0; im < 2; ++im)
#pragma unroll
        for (int in = 0; in < 2; ++in) {
          accg[im][in] = __builtin_amdgcn_mfma_f32_16x16x32_bf16(
              af[im], bg[in], accg[im][in], 0, 0, 0);
          accu[im][in] = __builtin_amdgcn_mfma_f32_16x16x32_bf16(
              af[im], bu[in], accu[im][in], 0, 0, 0);
        }
    }
  }

  const int off_e = offsets[e];
#pragma unroll
  for (int im = 0; im < 2; ++im) {
#pragma unroll
    for (int r = 0; r < 4; ++r) {
      const int row = wm + im * 16 + lq * 4 + r;  // C/D: row=(lane>>4)*4+reg
      const int slot = m0 + row;
      if (slot < count) {
        const float w = wt_s[row];
        uint16_t* hrow = hbuf + (size_t)(off_e + slot) * I_DIM + n0 + wn;
#pragma unroll
        for (int in = 0; in < 2; ++in) {
          const float g = accg[im][in][r];
          const float u = accu[im][in][r];
          const float hv = g / (1.f + __expf(-g)) * u * w;
          hrow[in * 16 + lc] = (uint16_t)f2bf(hv);  // C/D: col=lane&15
        }
      }
    }
  }
}

// ---------------------------------------------------------------------------
// Kernel 4: GEMM2  out[tok] += h @ down_wT   (per expert, atomic combine)
// BM=64 BN=64 BK=64, 4 waves (2x2 of 32x32).
// ---------------------------------------------------------------------------
__global__ __launch_bounds__(256, 4) void gemm2_kernel(
    const uint16_t* __restrict__ hbuf, const float* __restrict__ down,
    const int* __restrict__ counts, const int* __restrict__ offsets,
    const int* __restrict__ tokens, float* __restrict__ out) {
  const int e = blockIdx.z;
  const int count = counts[e];
  const int m0 = blockIdx.y * 64;
  if (m0 >= count) return;
  const int n0 = blockIdx.x * 64;

  __shared__ __align__(16) uint16_t As[64 * 64];
  __shared__ __align__(16) uint16_t Bs[64 * 64];
  __shared__ int tok_s[64];

  const int tid = threadIdx.x;
  const int off_e = offsets[e];
  if (tid < 64) {
    const int slot = m0 + tid;
    tok_s[tid] = (slot < count) ? tokens[e * T_TOK + slot] : 0;
  }
  __syncthreads();

  const int c0 = tid, c1 = tid + 256;
  const int m_a0 = c0 >> 3, m_a1 = c1 >> 3;
  const int kq0 = (c0 & 7) ^ (m_a0 & 7);
  const int kq1 = (c1 & 7) ^ (m_a1 & 7);

  int r0 = off_e + m0 + m_a0;
  int r1 = off_e + m0 + m_a1;
  if (r0 > TOTAL_ROWS - 1) r0 = TOTAL_ROWS - 1;  // ragged tail: junk rows,
  if (r1 > TOTAL_ROWS - 1) r1 = TOTAL_ROWS - 1;  // never stored
  const uint16_t* a_g0 = hbuf + (size_t)r0 * I_DIM + kq0 * 8;
  const uint16_t* a_g1 = hbuf + (size_t)r1 * I_DIM + kq1 * 8;
  uint16_t* a_l0 = As + c0 * 8;
  uint16_t* a_l1 = As + c1 * 8;

  const float* d_g0 = down + ((size_t)e * H_DIM + n0 + m_a0) * I_DIM + kq0 * 8;
  const float* d_g1 = down + ((size_t)e * H_DIM + n0 + m_a1) * I_DIM + kq1 * 8;
  uint16_t* b_l0 = Bs + c0 * 8;
  uint16_t* b_l1 = Bs + c1 * 8;

  const int wave = tid >> 6, lane = tid & 63;
  const int wm = (wave & 1) * 32, wn = (wave >> 1) * 32;
  const int lc = lane & 15, lq = lane >> 4;
  const int l7 = lc & 7;

  f32x4 acc[2][2];
  const f32x4 zero4 = {0.f, 0.f, 0.f, 0.f};
#pragma unroll
  for (int i = 0; i < 2; ++i)
#pragma unroll
    for (int j = 0; j < 2; ++j) acc[i][j] = zero4;

  const int am[2] = {(wm + lc) * 64, (wm + 16 + lc) * 64};
  const int bn[2] = {(wn + lc) * 64, (wn + 16 + lc) * 64};

  for (int k0 = 0; k0 < I_DIM; k0 += 64) {
    __syncthreads();
    async_copy16(a_g0 + k0, a_l0);
    async_copy16(a_g1 + k0, a_l1);
    stage8(d_g0 + k0, b_l0);
    stage8(d_g1 + k0, b_l1);
    __syncthreads();

#pragma unroll
    for (int ks = 0; ks < 2; ++ks) {
      const int kswz = (((ks * 4 + lq) ^ l7)) * 8;
      bf16x8 af[2], bf[2];
#pragma unroll
      for (int i = 0; i < 2; ++i) {
        af[i] = *(const bf16x8*)(As + am[i] + kswz);
        bf[i] = *(const bf16x8*)(Bs + bn[i] + kswz);
      }
#pragma unroll
      for (int im = 0; im < 2; ++im)
#pragma unroll
        for (int in = 0; in < 2; ++in)
          acc[im][in] = __builtin_amdgcn_mfma_f32_16x16x32_bf16(
              af[im], bf[in], acc[im][in], 0, 0, 0);
    }
  }

#pragma unroll
  for (int im = 0; im < 2; ++im) {
#pragma unroll
    for (int r = 0; r < 4; ++r) {
      const int row = wm + im * 16 + lq * 4 + r;
      const int slot = m0 + row;
      if (slot < count) {
        float* orow = out + (size_t)tok_s[row] * H_DIM + n0 + wn;
#pragma unroll
        for (int in = 0; in < 2; ++in)
          atomicAdd(orow + in * 16 + lc, acc[im][in][r]);
      }
    }
  }
}

// ---------------------------------------------------------------------------
extern "C" void kernel_launch(void* const* d_in, const int* in_sizes, int n_in,
                              void* d_out, int out_size, void* d_ws,
                              size_t ws_size, hipStream_t stream) {
  const float* x = (const float*)d_in[0];
  const float* rw = (const float*)d_in[1];
  const float* gate = (const float*)d_in[2];
  const float* up = (const float*)d_in[3];
  const float* down = (const float*)d_in[4];
  float* out = (float*)d_out;

  uint8_t* ws = (uint8_t*)d_ws;
  int* counts = (int*)ws;                                  // 16 ints
  int* offsets = (int*)(ws + 128);                         // 17 ints
  int* tokens = (int*)(ws + 1024);                         // 128 KiB
  float* wts = (float*)(ws + 1024 + 131072);               // 128 KiB
  uint16_t* xbf = (uint16_t*)(ws + 1024 + 262144);         // 4 MiB
  uint16_t* hbuf = (uint16_t*)(ws + 1024 + 262144 + 4194304);  // 8 MiB

  hipMemsetAsync(counts, 0, 128, stream);
  hipMemsetAsync(out, 0, (size_t)out_size * sizeof(float), stream);

  router_kernel<<<128, 256, 0, stream>>>(x, rw, xbf, counts, tokens, wts);
  offsets_kernel<<<1, 64, 0, stream>>>(counts, offsets);
  gemm1_kernel<<<dim3(16, 32, 16), 256, 0, stream>>>(
      xbf, gate, up, counts, offsets, tokens, wts, hbuf);
  gemm2_kernel<<<dim3(16, 32, 16), 256, 0, stream>>>(hbuf, down, counts,
                                                     offsets, tokens, out);
}

// Round 4
// 300.733 us; speedup vs baseline: 1.3245x; 1.2254x over previous
//
#include <hip/hip_runtime.h>
#include <stdint.h>

#define T_TOK 2048
#define H_DIM 1024
#define E_NUM 16
#define I_DIM 1024
#define TOTAL_ROWS (2 * T_TOK)   // exactly T*K assignment rows
#define CPAD 16                  // counts padded to one per 64B cacheline

typedef short bf16x8 __attribute__((ext_vector_type(8)));
typedef float f32x4 __attribute__((ext_vector_type(4)));

__device__ __forceinline__ void async_copy16(const void* g, void* l) {
  __builtin_amdgcn_global_load_lds(
      (const __attribute__((address_space(1))) void*)g,
      (__attribute__((address_space(3))) void*)l, 16, 0, 0);
}

// fp32 -> bf16 round-to-nearest-even (inputs finite)
__device__ __forceinline__ uint32_t f2bf(float f) {
  uint32_t u = __float_as_uint(f);
  return (u + 0x7FFFu + ((u >> 16) & 1u)) >> 16;
}
__device__ __forceinline__ uint32_t pk2bf(float lo, float hi) {
  return f2bf(lo) | (f2bf(hi) << 16);
}

// load 8 fp32, pack to 8 bf16, write 16B to LDS
__device__ __forceinline__ void stage8(const float* g, uint16_t* l) {
  float4 v0 = *(const float4*)g;
  float4 v1 = *(const float4*)(g + 4);
  uint4 p;
  p.x = pk2bf(v0.x, v0.y);
  p.y = pk2bf(v0.z, v0.w);
  p.z = pk2bf(v1.x, v1.y);
  p.w = pk2bf(v1.z, v1.w);
  *(uint4*)l = p;
}

// ---------------------------------------------------------------------------
// Kernel 1: router (fp32 exact) + x -> bf16 conversion. Wave-per-token.
// Butterfly reduce leaves all 16 scores in every lane; lanes 0/1 each commit
// one pick. Counters padded to separate cachelines (round-3: all 16 in ONE
// line -> 4096 serialized L2 RMWs = 85 us).
// ---------------------------------------------------------------------------
__global__ __launch_bounds__(256) void router_kernel(
    const float* __restrict__ x, const float* __restrict__ rw,
    uint16_t* __restrict__ xbf, int* __restrict__ counts,
    int* __restrict__ tokens, float* __restrict__ wts) {
  const int t = blockIdx.x * 4 + (threadIdx.x >> 6);  // token = wave id
  const int lane = threadIdx.x & 63;

  float4 xv[4];
  float acc[E_NUM];
#pragma unroll
  for (int e = 0; e < E_NUM; ++e) acc[e] = 0.f;

#pragma unroll
  for (int rep = 0; rep < 4; ++rep) {
    const int h0 = rep * 256 + lane * 4;
    xv[rep] = *(const float4*)(x + (size_t)t * H_DIM + h0);
    uint2 p;
    p.x = pk2bf(xv[rep].x, xv[rep].y);
    p.y = pk2bf(xv[rep].z, xv[rep].w);
    *(uint2*)(xbf + (size_t)t * H_DIM + h0) = p;
  }

#pragma unroll
  for (int e = 0; e < E_NUM; ++e) {
#pragma unroll
    for (int rep = 0; rep < 4; ++rep) {
      const float4 rv = *(const float4*)(rw + (size_t)e * H_DIM + rep * 256 + lane * 4);
      acc[e] += xv[rep].x * rv.x + xv[rep].y * rv.y + xv[rep].z * rv.z +
                xv[rep].w * rv.w;
    }
  }

#pragma unroll
  for (int e = 0; e < E_NUM; ++e) {
    float v = acc[e];
#pragma unroll
    for (int off = 32; off > 0; off >>= 1) v += __shfl_xor(v, off);
    acc[e] = v;  // every lane now holds the full sum
  }

  if (lane < 2) {
    float s[E_NUM];
#pragma unroll
    for (int e = 0; e < E_NUM; ++e) s[e] = 1.f / (1.f + expf(-acc[e]));
    // top-2, ties -> lower index (matches lax.top_k)
    int i1 = 0;
    float v1 = s[0];
#pragma unroll
    for (int e = 1; e < E_NUM; ++e)
      if (s[e] > v1) { v1 = s[e]; i1 = e; }
    int i2 = -1;
    float v2 = -1.f;
#pragma unroll
    for (int e = 0; e < E_NUM; ++e)
      if (e != i1 && s[e] > v2) { v2 = s[e]; i2 = e; }
    const float inv = 1.f / (v1 + v2 + 1e-20f);
    const int pe = (lane == 0) ? i1 : i2;
    const float pw = ((lane == 0) ? v1 : v2) * inv;
    const int slot = atomicAdd(&counts[pe * CPAD], 1);
    tokens[pe * T_TOK + slot] = t;
    wts[pe * T_TOK + slot] = pw;
  }
}

// ---------------------------------------------------------------------------
// Kernel 2: exclusive prefix sum over the 16 (padded) expert counts.
// ---------------------------------------------------------------------------
__global__ void offsets_kernel(const int* __restrict__ counts,
                               int* __restrict__ offsets) {
  if (threadIdx.x == 0) {
    int a = 0;
    for (int e = 0; e < E_NUM; ++e) {
      offsets[e] = a;
      a += counts[e * CPAD];
    }
    offsets[E_NUM] = a;
  }
}

// ---------------------------------------------------------------------------
// LDS tile layout (both GEMMs): 64 rows x 64 k of bf16, stored as 16B chunks.
// chunk(m,kq) lives at index m*8 + (kq ^ (m&7)); the XOR spreads the 8
// fragment rows a b128 read touches across all 8 bank clusters.
// ---------------------------------------------------------------------------

// ---------------------------------------------------------------------------
// Kernel 3: GEMM1  h = silu(x@gateT) * (x@upT) * route_wt   (per expert)
// BM=64 BN=64 BK=64, 4 waves (2x2 of 32x32), dual gate/up accumulators.
// ---------------------------------------------------------------------------
__global__ __launch_bounds__(256, 4) void gemm1_kernel(
    const uint16_t* __restrict__ xbf, const float* __restrict__ gate,
    const float* __restrict__ up, const int* __restrict__ counts,
    const int* __restrict__ offsets, const int* __restrict__ tokens,
    const float* __restrict__ wts, uint16_t* __restrict__ hbuf) {
  const int e = blockIdx.z;
  const int count = counts[e * CPAD];
  const int m0 = blockIdx.y * 64;
  if (m0 >= count) return;
  const int n0 = blockIdx.x * 64;

  __shared__ __align__(16) uint16_t As[64 * 64];
  __shared__ __align__(16) uint16_t Bgs[64 * 64];
  __shared__ __align__(16) uint16_t Bus[64 * 64];
  __shared__ int tok_s[64];
  __shared__ float wt_s[64];

  const int tid = threadIdx.x;
  if (tid < 64) {
    const int slot = m0 + tid;
    int tk = 0;
    float w = 0.f;
    if (slot < count) {
      tk = tokens[e * T_TOK + slot];
      w = wts[e * T_TOK + slot];
    }
    tok_s[tid] = tk;
    wt_s[tid] = w;
  }
  __syncthreads();

  // Two 16B chunks per thread per tile: c0=tid, c1=tid+256.
  const int c0 = tid, c1 = tid + 256;
  const int m_a0 = c0 >> 3, m_a1 = c1 >> 3;
  const int kq0 = (c0 & 7) ^ (m_a0 & 7);
  const int kq1 = (c1 & 7) ^ (m_a1 & 7);

  const uint16_t* a_g0 = xbf + (size_t)tok_s[m_a0] * H_DIM + kq0 * 8;
  const uint16_t* a_g1 = xbf + (size_t)tok_s[m_a1] * H_DIM + kq1 * 8;
  uint16_t* a_l0 = As + c0 * 8;
  uint16_t* a_l1 = As + c1 * 8;

  const float* g_g0 = gate + ((size_t)e * I_DIM + n0 + m_a0) * H_DIM + kq0 * 8;
  const float* g_g1 = gate + ((size_t)e * I_DIM + n0 + m_a1) * H_DIM + kq1 * 8;
  const float* u_g0 = up + ((size_t)e * I_DIM + n0 + m_a0) * H_DIM + kq0 * 8;
  const float* u_g1 = up + ((size_t)e * I_DIM + n0 + m_a1) * H_DIM + kq1 * 8;
  uint16_t* bg_l0 = Bgs + c0 * 8;
  uint16_t* bg_l1 = Bgs + c1 * 8;
  uint16_t* bu_l0 = Bus + c0 * 8;
  uint16_t* bu_l1 = Bus + c1 * 8;

  const int wave = tid >> 6, lane = tid & 63;
  const int wm = (wave & 1) * 32, wn = (wave >> 1) * 32;
  const int lc = lane & 15, lq = lane >> 4;
  const int l7 = lc & 7;  // (row&7) for every fragment row (rows step by 16)

  f32x4 accg[2][2], accu[2][2];
  const f32x4 zero4 = {0.f, 0.f, 0.f, 0.f};
#pragma unroll
  for (int i = 0; i < 2; ++i)
#pragma unroll
    for (int j = 0; j < 2; ++j) {
      accg[i][j] = zero4;
      accu[i][j] = zero4;
    }

  const int am[2] = {(wm + lc) * 64, (wm + 16 + lc) * 64};
  const int bn[2] = {(wn + lc) * 64, (wn + 16 + lc) * 64};

  for (int k0 = 0; k0 < H_DIM; k0 += 64) {
    __syncthreads();
    async_copy16(a_g0 + k0, a_l0);
    async_copy16(a_g1 + k0, a_l1);
    stage8(g_g0 + k0, bg_l0);
    stage8(g_g1 + k0, bg_l1);
    stage8(u_g0 + k0, bu_l0);
    stage8(u_g1 + k0, bu_l1);
    __syncthreads();

#pragma unroll
    for (int ks = 0; ks < 2; ++ks) {
      const int kswz = (((ks * 4 + lq) ^ l7)) * 8;
      bf16x8 af[2], bg[2], bu[2];
#pragma unroll
      for (int i = 0; i < 2; ++i) {
        af[i] = *(const bf16x8*)(As + am[i] + kswz);
        bg[i] = *(const bf16x8*)(Bgs + bn[i] + kswz);
        bu[i] = *(const bf16x8*)(Bus + bn[i] + kswz);
      }
#pragma unroll
      for (int im = 0; im < 2; ++im)
#pragma unroll
        for (int in = 0; in < 2; ++in) {
          accg[im][in] = __builtin_amdgcn_mfma_f32_16x16x32_bf16(
              af[im], bg[in], accg[im][in], 0, 0, 0);
          accu[im][in] = __builtin_amdgcn_mfma_f32_16x16x32_bf16(
              af[im], bu[in], accu[im][in], 0, 0, 0);
        }
    }
  }

  const int off_e = offsets[e];
#pragma unroll
  for (int im = 0; im < 2; ++im) {
#pragma unroll
    for (int r = 0; r < 4; ++r) {
      const int row = wm + im * 16 + lq * 4 + r;  // C/D: row=(lane>>4)*4+reg
      const int slot = m0 + row;
      if (slot < count) {
        const float w = wt_s[row];
        uint16_t* hrow = hbuf + (size_t)(off_e + slot) * I_DIM + n0 + wn;
#pragma unroll
        for (int in = 0; in < 2; ++in) {
          const float g = accg[im][in][r];
          const float u = accu[im][in][r];
          const float hv = g / (1.f + __expf(-g)) * u * w;
          hrow[in * 16 + lc] = (uint16_t)f2bf(hv);  // C/D: col=lane&15
        }
      }
    }
  }
}

// ---------------------------------------------------------------------------
// Kernel 4: GEMM2  out[tok] += h @ down_wT   (per expert, atomic combine)
// BM=64 BN=64 BK=64, 4 waves (2x2 of 32x32).
// ---------------------------------------------------------------------------
__global__ __launch_bounds__(256, 4) void gemm2_kernel(
    const uint16_t* __restrict__ hbuf, const float* __restrict__ down,
    const int* __restrict__ counts, const int* __restrict__ offsets,
    const int* __restrict__ tokens, float* __restrict__ out) {
  const int e = blockIdx.z;
  const int count = counts[e * CPAD];
  const int m0 = blockIdx.y * 64;
  if (m0 >= count) return;
  const int n0 = blockIdx.x * 64;

  __shared__ __align__(16) uint16_t As[64 * 64];
  __shared__ __align__(16) uint16_t Bs[64 * 64];
  __shared__ int tok_s[64];

  const int tid = threadIdx.x;
  const int off_e = offsets[e];
  if (tid < 64) {
    const int slot = m0 + tid;
    tok_s[tid] = (slot < count) ? tokens[e * T_TOK + slot] : 0;
  }
  __syncthreads();

  const int c0 = tid, c1 = tid + 256;
  const int m_a0 = c0 >> 3, m_a1 = c1 >> 3;
  const int kq0 = (c0 & 7) ^ (m_a0 & 7);
  const int kq1 = (c1 & 7) ^ (m_a1 & 7);

  int r0 = off_e + m0 + m_a0;
  int r1 = off_e + m0 + m_a1;
  if (r0 > TOTAL_ROWS - 1) r0 = TOTAL_ROWS - 1;  // ragged tail: junk rows,
  if (r1 > TOTAL_ROWS - 1) r1 = TOTAL_ROWS - 1;  // never stored
  const uint16_t* a_g0 = hbuf + (size_t)r0 * I_DIM + kq0 * 8;
  const uint16_t* a_g1 = hbuf + (size_t)r1 * I_DIM + kq1 * 8;
  uint16_t* a_l0 = As + c0 * 8;
  uint16_t* a_l1 = As + c1 * 8;

  const float* d_g0 = down + ((size_t)e * H_DIM + n0 + m_a0) * I_DIM + kq0 * 8;
  const float* d_g1 = down + ((size_t)e * H_DIM + n0 + m_a1) * I_DIM + kq1 * 8;
  uint16_t* b_l0 = Bs + c0 * 8;
  uint16_t* b_l1 = Bs + c1 * 8;

  const int wave = tid >> 6, lane = tid & 63;
  const int wm = (wave & 1) * 32, wn = (wave >> 1) * 32;
  const int lc = lane & 15, lq = lane >> 4;
  const int l7 = lc & 7;

  f32x4 acc[2][2];
  const f32x4 zero4 = {0.f, 0.f, 0.f, 0.f};
#pragma unroll
  for (int i = 0; i < 2; ++i)
#pragma unroll
    for (int j = 0; j < 2; ++j) acc[i][j] = zero4;

  const int am[2] = {(wm + lc) * 64, (wm + 16 + lc) * 64};
  const int bn[2] = {(wn + lc) * 64, (wn + 16 + lc) * 64};

  for (int k0 = 0; k0 < I_DIM; k0 += 64) {
    __syncthreads();
    async_copy16(a_g0 + k0, a_l0);
    async_copy16(a_g1 + k0, a_l1);
    stage8(d_g0 + k0, b_l0);
    stage8(d_g1 + k0, b_l1);
    __syncthreads();

#pragma unroll
    for (int ks = 0; ks < 2; ++ks) {
      const int kswz = (((ks * 4 + lq) ^ l7)) * 8;
      bf16x8 af[2], bf[2];
#pragma unroll
      for (int i = 0; i < 2; ++i) {
        af[i] = *(const bf16x8*)(As + am[i] + kswz);
        bf[i] = *(const bf16x8*)(Bs + bn[i] + kswz);
      }
#pragma unroll
      for (int im = 0; im < 2; ++im)
#pragma unroll
        for (int in = 0; in < 2; ++in)
          acc[im][in] = __builtin_amdgcn_mfma_f32_16x16x32_bf16(
              af[im], bf[in], acc[im][in], 0, 0, 0);
    }
  }

#pragma unroll
  for (int im = 0; im < 2; ++im) {
#pragma unroll
    for (int r = 0; r < 4; ++r) {
      const int row = wm + im * 16 + lq * 4 + r;
      const int slot = m0 + row;
      if (slot < count) {
        float* orow = out + (size_t)tok_s[row] * H_DIM + n0 + wn;
#pragma unroll
        for (int in = 0; in < 2; ++in)
          atomicAdd(orow + in * 16 + lc, acc[im][in][r]);
      }
    }
  }
}

// ---------------------------------------------------------------------------
extern "C" void kernel_launch(void* const* d_in, const int* in_sizes, int n_in,
                              void* d_out, int out_size, void* d_ws,
                              size_t ws_size, hipStream_t stream) {
  const float* x = (const float*)d_in[0];
  const float* rw = (const float*)d_in[1];
  const float* gate = (const float*)d_in[2];
  const float* up = (const float*)d_in[3];
  const float* down = (const float*)d_in[4];
  float* out = (float*)d_out;

  uint8_t* ws = (uint8_t*)d_ws;
  int* counts = (int*)ws;                                  // 16 * 64B padded
  int* offsets = (int*)(ws + 2048);                        // 17 ints
  int* tokens = (int*)(ws + 4096);                         // 128 KiB
  float* wts = (float*)(ws + 4096 + 131072);               // 128 KiB
  uint16_t* xbf = (uint16_t*)(ws + 4096 + 262144);         // 4 MiB
  uint16_t* hbuf = (uint16_t*)(ws + 4096 + 262144 + 4194304);  // 8 MiB

  hipMemsetAsync(counts, 0, 2048, stream);
  hipMemsetAsync(out, 0, (size_t)out_size * sizeof(float), stream);

  router_kernel<<<512, 256, 0, stream>>>(x, rw, xbf, counts, tokens, wts);
  offsets_kernel<<<1, 64, 0, stream>>>(counts, offsets);
  gemm1_kernel<<<dim3(16, 32, 16), 256, 0, stream>>>(
      xbf, gate, up, counts, offsets, tokens, wts, hbuf);
  gemm2_kernel<<<dim3(16, 32, 16), 256, 0, stream>>>(hbuf, down, counts,
                                                     offsets, tokens, out);
}

// Round 5
// 285.005 us; speedup vs baseline: 1.3976x; 1.0552x over previous
//
#include <hip/hip_runtime.h>
#include <stdint.h>

#define T_TOK 2048
#define H_DIM 1024
#define E_NUM 16
#define I_DIM 1024
#define TOTAL_ROWS (2 * T_TOK)   // exactly T*K assignment rows
#define CPAD 16                  // counts padded to one per 64B cacheline

typedef short bf16x8 __attribute__((ext_vector_type(8)));
typedef float f32x4 __attribute__((ext_vector_type(4)));

__device__ __forceinline__ void async_copy16(const void* g, void* l) {
  __builtin_amdgcn_global_load_lds(
      (const __attribute__((address_space(1))) void*)g,
      (__attribute__((address_space(3))) void*)l, 16, 0, 0);
}

// fp32 -> bf16 round-to-nearest-even (inputs finite)
__device__ __forceinline__ uint32_t f2bf(float f) {
  uint32_t u = __float_as_uint(f);
  return (u + 0x7FFFu + ((u >> 16) & 1u)) >> 16;
}
__device__ __forceinline__ uint32_t pk2bf(float lo, float hi) {
  return f2bf(lo) | (f2bf(hi) << 16);
}

// ---------------------------------------------------------------------------
// Kernel 1: router (fp32 exact) + x -> bf16 conversion. Wave-per-token.
// Counters padded one per cacheline (single-line atomics serialized = 85us).
// ---------------------------------------------------------------------------
__global__ __launch_bounds__(256) void router_kernel(
    const float* __restrict__ x, const float* __restrict__ rw,
    uint16_t* __restrict__ xbf, int* __restrict__ counts,
    int* __restrict__ tokens, float* __restrict__ wts) {
  const int t = blockIdx.x * 4 + (threadIdx.x >> 6);  // token = wave id
  const int lane = threadIdx.x & 63;

  float4 xv[4];
  float acc[E_NUM];
#pragma unroll
  for (int e = 0; e < E_NUM; ++e) acc[e] = 0.f;

#pragma unroll
  for (int rep = 0; rep < 4; ++rep) {
    const int h0 = rep * 256 + lane * 4;
    xv[rep] = *(const float4*)(x + (size_t)t * H_DIM + h0);
    uint2 p;
    p.x = pk2bf(xv[rep].x, xv[rep].y);
    p.y = pk2bf(xv[rep].z, xv[rep].w);
    *(uint2*)(xbf + (size_t)t * H_DIM + h0) = p;
  }

#pragma unroll
  for (int e = 0; e < E_NUM; ++e) {
#pragma unroll
    for (int rep = 0; rep < 4; ++rep) {
      const float4 rv = *(const float4*)(rw + (size_t)e * H_DIM + rep * 256 + lane * 4);
      acc[e] += xv[rep].x * rv.x + xv[rep].y * rv.y + xv[rep].z * rv.z +
                xv[rep].w * rv.w;
    }
  }

#pragma unroll
  for (int e = 0; e < E_NUM; ++e) {
    float v = acc[e];
#pragma unroll
    for (int off = 32; off > 0; off >>= 1) v += __shfl_xor(v, off);
    acc[e] = v;  // every lane now holds the full sum
  }

  if (lane < 2) {
    float s[E_NUM];
#pragma unroll
    for (int e = 0; e < E_NUM; ++e) s[e] = 1.f / (1.f + expf(-acc[e]));
    // top-2, ties -> lower index (matches lax.top_k)
    int i1 = 0;
    float v1 = s[0];
#pragma unroll
    for (int e = 1; e < E_NUM; ++e)
      if (s[e] > v1) { v1 = s[e]; i1 = e; }
    int i2 = -1;
    float v2 = -1.f;
#pragma unroll
    for (int e = 0; e < E_NUM; ++e)
      if (e != i1 && s[e] > v2) { v2 = s[e]; i2 = e; }
    const float inv = 1.f / (v1 + v2 + 1e-20f);
    const int pe = (lane == 0) ? i1 : i2;
    const float pw = ((lane == 0) ? v1 : v2) * inv;
    const int slot = atomicAdd(&counts[pe * CPAD], 1);
    tokens[pe * T_TOK + slot] = t;
    wts[pe * T_TOK + slot] = pw;
  }
}

// ---------------------------------------------------------------------------
// Kernel 2: exclusive prefix sum over the 16 (padded) expert counts.
// ---------------------------------------------------------------------------
__global__ void offsets_kernel(const int* __restrict__ counts,
                               int* __restrict__ offsets) {
  if (threadIdx.x == 0) {
    int a = 0;
    for (int e = 0; e < E_NUM; ++e) {
      offsets[e] = a;
      a += counts[e * CPAD];
    }
    offsets[E_NUM] = a;
  }
}

// ---------------------------------------------------------------------------
// LDS tile layout: rows x 64k bf16 in 16B chunks; chunk(m,kq) at index
// m*8 + (kq ^ (m&7)) — XOR spreads fragment-read banks (0 conflicts, R4).
//
// BM=256 rationale (R4 post-mortem): with BM=64 each expert's fp32 weight
// strip was re-read by 8 m-tiles => ~1.2 GB LLC-side traffic = 14 TB/s
// (invisible to FETCH_SIZE) — the real limiter. BM=256 cuts B re-reads to
// 2x. B fp32 is register-prefetched AFTER the compute barrier so its
// vmcnt drain is covered by the MFMA phase.
// ---------------------------------------------------------------------------

// ---------------------------------------------------------------------------
// Kernel 3: GEMM1  h = silu(x@gateT) * (x@upT) * route_wt   (per expert)
// BM=256 BN=64 BK=64, 512 thr (8 waves of 64m x 32n), dual gate/up acc.
// ---------------------------------------------------------------------------
__global__ __launch_bounds__(512, 4) void gemm1_kernel(
    const uint16_t* __restrict__ xbf, const float* __restrict__ gate,
    const float* __restrict__ up, const int* __restrict__ counts,
    const int* __restrict__ offsets, const int* __restrict__ tokens,
    const float* __restrict__ wts, uint16_t* __restrict__ hbuf) {
  const int e = blockIdx.z;
  const int count = counts[e * CPAD];
  const int m0 = blockIdx.y * 256;
  if (m0 >= count) return;
  const int n0 = blockIdx.x * 64;

  __shared__ __align__(16) uint16_t As[256 * 64];   // 32 KB
  __shared__ __align__(16) uint16_t Bgs[64 * 64];   // 8 KB
  __shared__ __align__(16) uint16_t Bus[64 * 64];   // 8 KB
  __shared__ int tok_s[256];
  __shared__ float wt_s[256];

  const int tid = threadIdx.x;
  if (tid < 256) {
    const int slot = m0 + tid;
    int tk = 0;
    float w = 0.f;
    if (slot < count) {
      tk = tokens[e * T_TOK + slot];
      w = wts[e * T_TOK + slot];
    }
    tok_s[tid] = tk;
    wt_s[tid] = w;
  }
  __syncthreads();

  // A: 2048 16B chunks, 4 per thread (c = j*512 + tid)
  const uint16_t* a_g[4];
  uint16_t* a_l[4];
#pragma unroll
  for (int j = 0; j < 4; ++j) {
    const int c = j * 512 + tid;
    const int m = c >> 3;
    const int kq = (c & 7) ^ (m & 7);
    a_g[j] = xbf + (size_t)tok_s[m] * H_DIM + kq * 8;
    a_l[j] = As + c * 8;
  }
  // B: 512 chunks, 1 per thread per matrix
  const int bm = tid >> 3;
  const int bkq = (tid & 7) ^ (bm & 7);
  const float* g_g = gate + ((size_t)e * I_DIM + n0 + bm) * H_DIM + bkq * 8;
  const float* u_g = up + ((size_t)e * I_DIM + n0 + bm) * H_DIM + bkq * 8;
  uint16_t* bg_l = Bgs + tid * 8;
  uint16_t* bu_l = Bus + tid * 8;

  const int wave = tid >> 6, lane = tid & 63;
  const int wm = (wave & 3) * 64, wn = (wave >> 2) * 32;
  const int lc = lane & 15, lq = lane >> 4;
  const int l7 = lc & 7;

  f32x4 accg[4][2], accu[4][2];
  const f32x4 zero4 = {0.f, 0.f, 0.f, 0.f};
#pragma unroll
  for (int i = 0; i < 4; ++i)
#pragma unroll
    for (int j = 0; j < 2; ++j) {
      accg[i][j] = zero4;
      accu[i][j] = zero4;
    }

  int am[4], bn[2];
#pragma unroll
  for (int i = 0; i < 4; ++i) am[i] = (wm + i * 16 + lc) * 64;
#pragma unroll
  for (int i = 0; i < 2; ++i) bn[i] = (wn + i * 16 + lc) * 64;

  // register prefetch of this iteration's fp32 B (gate+up)
  float4 gr0 = *(const float4*)g_g;
  float4 gr1 = *(const float4*)(g_g + 4);
  float4 ur0 = *(const float4*)u_g;
  float4 ur1 = *(const float4*)(u_g + 4);

  for (int k0 = 0; k0 < H_DIM; k0 += 64) {
    __syncthreads();  // previous tile fully consumed
#pragma unroll
    for (int j = 0; j < 4; ++j) async_copy16(a_g[j] + k0, a_l[j]);
    uint4 p;
    p.x = pk2bf(gr0.x, gr0.y);
    p.y = pk2bf(gr0.z, gr0.w);
    p.z = pk2bf(gr1.x, gr1.y);
    p.w = pk2bf(gr1.z, gr1.w);
    *(uint4*)bg_l = p;
    p.x = pk2bf(ur0.x, ur0.y);
    p.y = pk2bf(ur0.z, ur0.w);
    p.z = pk2bf(ur1.x, ur1.y);
    p.w = pk2bf(ur1.z, ur1.w);
    *(uint4*)bu_l = p;
    __syncthreads();  // A landed, B visible
    // prefetch next iteration's B here: drain happens at next barrier,
    // covered by the MFMA phase below
    if (k0 + 64 < H_DIM) {
      gr0 = *(const float4*)(g_g + k0 + 64);
      gr1 = *(const float4*)(g_g + k0 + 68);
      ur0 = *(const float4*)(u_g + k0 + 64);
      ur1 = *(const float4*)(u_g + k0 + 68);
    }

#pragma unroll
    for (int ks = 0; ks < 2; ++ks) {
      const int kswz = ((ks * 4 + lq) ^ l7) * 8;
      bf16x8 af[4], bg[2], bu[2];
#pragma unroll
      for (int i = 0; i < 4; ++i) af[i] = *(const bf16x8*)(As + am[i] + kswz);
#pragma unroll
      for (int i = 0; i < 2; ++i) {
        bg[i] = *(const bf16x8*)(Bgs + bn[i] + kswz);
        bu[i] = *(const bf16x8*)(Bus + bn[i] + kswz);
      }
#pragma unroll
      for (int im = 0; im < 4; ++im)
#pragma unroll
        for (int in = 0; in < 2; ++in) {
          accg[im][in] = __builtin_amdgcn_mfma_f32_16x16x32_bf16(
              af[im], bg[in], accg[im][in], 0, 0, 0);
          accu[im][in] = __builtin_amdgcn_mfma_f32_16x16x32_bf16(
              af[im], bu[in], accu[im][in], 0, 0, 0);
        }
    }
  }

  const int off_e = offsets[e];
#pragma unroll
  for (int im = 0; im < 4; ++im) {
#pragma unroll
    for (int r = 0; r < 4; ++r) {
      const int row = wm + im * 16 + lq * 4 + r;  // C/D: row=(lane>>4)*4+reg
      const int slot = m0 + row;
      if (slot < count) {
        const float w = wt_s[row];
        uint16_t* hrow = hbuf + (size_t)(off_e + slot) * I_DIM + n0 + wn;
#pragma unroll
        for (int in = 0; in < 2; ++in) {
          const float g = accg[im][in][r];
          const float u = accu[im][in][r];
          const float hv = g / (1.f + __expf(-g)) * u * w;
          hrow[in * 16 + lc] = (uint16_t)f2bf(hv);  // C/D: col=lane&15
        }
      }
    }
  }
}

// ---------------------------------------------------------------------------
// Kernel 4: GEMM2  out[tok] += h @ down_wT   (per expert, atomic combine)
// BM=256 BN=64 BK=64, 512 thr (8 waves of 64m x 32n).
// ---------------------------------------------------------------------------
__global__ __launch_bounds__(512, 4) void gemm2_kernel(
    const uint16_t* __restrict__ hbuf, const float* __restrict__ down,
    const int* __restrict__ counts, const int* __restrict__ offsets,
    const int* __restrict__ tokens, float* __restrict__ out) {
  const int e = blockIdx.z;
  const int count = counts[e * CPAD];
  const int m0 = blockIdx.y * 256;
  if (m0 >= count) return;
  const int n0 = blockIdx.x * 64;

  __shared__ __align__(16) uint16_t As[256 * 64];  // 32 KB
  __shared__ __align__(16) uint16_t Bs[64 * 64];   // 8 KB
  __shared__ int tok_s[256];

  const int tid = threadIdx.x;
  const int off_e = offsets[e];
  if (tid < 256) {
    const int slot = m0 + tid;
    tok_s[tid] = (slot < count) ? tokens[e * T_TOK + slot] : 0;
  }

  const uint16_t* a_g[4];
  uint16_t* a_l[4];
#pragma unroll
  for (int j = 0; j < 4; ++j) {
    const int c = j * 512 + tid;
    const int m = c >> 3;
    const int kq = (c & 7) ^ (m & 7);
    int r = off_e + m0 + m;
    if (r > TOTAL_ROWS - 1) r = TOTAL_ROWS - 1;  // ragged tail: junk rows,
    a_g[j] = hbuf + (size_t)r * I_DIM + kq * 8;   // never stored
    a_l[j] = As + c * 8;
  }
  const int bm = tid >> 3;
  const int bkq = (tid & 7) ^ (bm & 7);
  const float* d_g = down + ((size_t)e * H_DIM + n0 + bm) * I_DIM + bkq * 8;
  uint16_t* b_l = Bs + tid * 8;

  const int wave = tid >> 6, lane = tid & 63;
  const int wm = (wave & 3) * 64, wn = (wave >> 2) * 32;
  const int lc = lane & 15, lq = lane >> 4;
  const int l7 = lc & 7;

  f32x4 acc[4][2];
  const f32x4 zero4 = {0.f, 0.f, 0.f, 0.f};
#pragma unroll
  for (int i = 0; i < 4; ++i)
#pragma unroll
    for (int j = 0; j < 2; ++j) acc[i][j] = zero4;

  int am[4], bn[2];
#pragma unroll
  for (int i = 0; i < 4; ++i) am[i] = (wm + i * 16 + lc) * 64;
#pragma unroll
  for (int i = 0; i < 2; ++i) bn[i] = (wn + i * 16 + lc) * 64;

  __syncthreads();  // tok_s visible (a_g uses off_e only, but keep ordering)

  float4 dr0 = *(const float4*)d_g;
  float4 dr1 = *(const float4*)(d_g + 4);

  for (int k0 = 0; k0 < I_DIM; k0 += 64) {
    __syncthreads();
#pragma unroll
    for (int j = 0; j < 4; ++j) async_copy16(a_g[j] + k0, a_l[j]);
    uint4 p;
    p.x = pk2bf(dr0.x, dr0.y);
    p.y = pk2bf(dr0.z, dr0.w);
    p.z = pk2bf(dr1.x, dr1.y);
    p.w = pk2bf(dr1.z, dr1.w);
    *(uint4*)b_l = p;
    __syncthreads();
    if (k0 + 64 < I_DIM) {
      dr0 = *(const float4*)(d_g + k0 + 64);
      dr1 = *(const float4*)(d_g + k0 + 68);
    }

#pragma unroll
    for (int ks = 0; ks < 2; ++ks) {
      const int kswz = ((ks * 4 + lq) ^ l7) * 8;
      bf16x8 af[4], bf[2];
#pragma unroll
      for (int i = 0; i < 4; ++i) af[i] = *(const bf16x8*)(As + am[i] + kswz);
#pragma unroll
      for (int i = 0; i < 2; ++i) bf[i] = *(const bf16x8*)(Bs + bn[i] + kswz);
#pragma unroll
      for (int im = 0; im < 4; ++im)
#pragma unroll
        for (int in = 0; in < 2; ++in)
          acc[im][in] = __builtin_amdgcn_mfma_f32_16x16x32_bf16(
              af[im], bf[in], acc[im][in], 0, 0, 0);
    }
  }

#pragma unroll
  for (int im = 0; im < 4; ++im) {
#pragma unroll
    for (int r = 0; r < 4; ++r) {
      const int row = wm + im * 16 + lq * 4 + r;
      const int slot = m0 + row;
      if (slot < count) {
        float* orow = out + (size_t)tok_s[row] * H_DIM + n0 + wn;
#pragma unroll
        for (int in = 0; in < 2; ++in)
          atomicAdd(orow + in * 16 + lc, acc[im][in][r]);
      }
    }
  }
}

// ---------------------------------------------------------------------------
extern "C" void kernel_launch(void* const* d_in, const int* in_sizes, int n_in,
                              void* d_out, int out_size, void* d_ws,
                              size_t ws_size, hipStream_t stream) {
  const float* x = (const float*)d_in[0];
  const float* rw = (const float*)d_in[1];
  const float* gate = (const float*)d_in[2];
  const float* up = (const float*)d_in[3];
  const float* down = (const float*)d_in[4];
  float* out = (float*)d_out;

  uint8_t* ws = (uint8_t*)d_ws;
  int* counts = (int*)ws;                                  // 16 * 64B padded
  int* offsets = (int*)(ws + 2048);                        // 17 ints
  int* tokens = (int*)(ws + 4096);                         // 128 KiB
  float* wts = (float*)(ws + 4096 + 131072);               // 128 KiB
  uint16_t* xbf = (uint16_t*)(ws + 4096 + 262144);         // 4 MiB
  uint16_t* hbuf = (uint16_t*)(ws + 4096 + 262144 + 4194304);  // 8 MiB

  hipMemsetAsync(counts, 0, 2048, stream);
  hipMemsetAsync(out, 0, (size_t)out_size * sizeof(float), stream);

  router_kernel<<<512, 256, 0, stream>>>(x, rw, xbf, counts, tokens, wts);
  offsets_kernel<<<1, 64, 0, stream>>>(counts, offsets);
  gemm1_kernel<<<dim3(16, 8, 16), 512, 0, stream>>>(
      xbf, gate, up, counts, offsets, tokens, wts, hbuf);
  gemm2_kernel<<<dim3(16, 8, 16), 512, 0, stream>>>(hbuf, down, counts,
                                                    offsets, tokens, out);
}